// Round 8
// baseline (440.804 us; speedup 1.0000x reference)
//
#include <hip/hip_runtime.h>
#include <hip/hip_bf16.h>
#include <hip/hip_fp16.h>

// R8: move the V transpose out of the attention hot loops.  The qkv GEMM's
// epilogue (SPLITV path) writes V columns directly to Vt[b][h*64+d][key]
// (packed f16x4 8B stores; C/D frag rows are 4 consecutive tokens at fixed d)
// and Q/K to a slimmed qkvbuf (ldc=1024).  full_attn stages Vs from Vt with
// 2 vector LDS writes/thread (was 32 scalar writes => 9.4M bank conflicts);
// win_attn loses its V LDS entirely (PV B-frags = contiguous f16x8 global
// loads from Vt, clamped + masked at the left edge).  ws is net-zero:
// qkvbuf 50.3->33.6 MB, Vt takes the freed 16.8 MB.

using f16 = _Float16;
typedef _Float16 f16x4 __attribute__((ext_vector_type(4)));
typedef _Float16 f16x8 __attribute__((ext_vector_type(8)));
typedef float    f32x4 __attribute__((ext_vector_type(4)));

__device__ inline void storeC(float* p, float v) { *p = v; }
__device__ inline void storeC(f16* p, float v)   { *p = (f16)v; }

// async 16B global -> LDS (dest = wave-uniform base + lane*16)
__device__ inline void async_cp16(const f16* g, f16* l) {
    __builtin_amdgcn_global_load_lds(
        (const __attribute__((address_space(1))) unsigned int*)g,
        (__attribute__((address_space(3))) unsigned int*)l,
        16, 0, 0);
}

// ---------------------------------------------------------------------------
// fp32 -> fp16 conversion, 8 elements/thread
// ---------------------------------------------------------------------------
__global__ __launch_bounds__(256) void f32_to_f16(
    const float* __restrict__ in, f16* __restrict__ out, int n)
{
    int i = (blockIdx.x * 256 + threadIdx.x) * 8;
    if (i >= n) return;
    float4 a = *(const float4*)(in + i);
    float4 b = *(const float4*)(in + i + 4);
    f16x8 h = { (f16)a.x, (f16)a.y, (f16)a.z, (f16)a.w,
                (f16)b.x, (f16)b.y, (f16)b.z, (f16)b.w };
    *(f16x8*)(out + i) = h;
}

// ---------------------------------------------------------------------------
// Wo[z] (512x512 f32) -> WoT[z] (512x512 f16), WoT[d][c] = Wo[c][d]
// ---------------------------------------------------------------------------
__global__ __launch_bounds__(256) void transpose_wo(
    const float* __restrict__ Wo, f16* __restrict__ WoT)
{
    __shared__ float t[32][33];
    const int z = blockIdx.z;
    const int bx = blockIdx.x * 32;
    const int by = blockIdx.y * 32;
    const int tx = threadIdx.x & 31;
    const int ty = threadIdx.x >> 5;
#pragma unroll
    for (int r = ty; r < 32; r += 8)
        t[r][tx] = Wo[(size_t)z * 262144 + (by + r) * 512 + bx + tx];
    __syncthreads();
#pragma unroll
    for (int r = ty; r < 32; r += 8)
        WoT[(size_t)z * 262144 + (bx + r) * 512 + by + tx] = (f16)t[tx][r];
}

// ---------------------------------------------------------------------------
// b'[o] = bf[o] + sum_j Wf[o][j] * bo_flat[j]   (one wave per o)
// ---------------------------------------------------------------------------
__global__ __launch_bounds__(256) void bias_fuse(
    const float* __restrict__ Wf, const float* __restrict__ bo,
    const float* __restrict__ bfv, float* __restrict__ bp)
{
    const int o = blockIdx.x * 4 + (threadIdx.x >> 6);
    const int lane = threadIdx.x & 63;
    float s = 0.f;
    for (int j = lane; j < 1536; j += 64) s += Wf[o * 1536 + j] * bo[j];
#pragma unroll
    for (int msk = 1; msk < 64; msk <<= 1) s += __shfl_xor(s, msk, 64);
    if (lane == 0) bp[o] = s + bfv[o];
}

// ---------------------------------------------------------------------------
// MFMA GEMM:  C[m,n] = sum_k A[m,k]*B[n,k] (+ bias[n])   (NT, fp16 in)
// z-batched via blockIdx.z (strides azs/bzs/czs). bias nullable.
// SPLITV: cols [0,1024) -> C (ldc), cols [1024,1536) -> Vt[b][col-1024][s]
// as packed f16x4 stores (4 consecutive tokens per C/D quad).
// ---------------------------------------------------------------------------
template <typename TC, bool SPLITV>
__global__ __launch_bounds__(256) void gemm_mfma_nt(
    const f16* __restrict__ A, int lda, long azs,
    const f16* __restrict__ B, int ldb, long bzs,
    const float* __restrict__ bias,
    TC* __restrict__ C, int ldc, long czs,
    int K, f16* __restrict__ Vt)
{
    __shared__ __align__(16) f16 As[128 * 32];
    __shared__ __align__(16) f16 Bs[128 * 32];

    const int tid  = threadIdx.x;
    const int lane = tid & 63;
    const int wave = tid >> 6;
    const int wm = (wave >> 1) * 64;
    const int wn = (wave & 1) * 64;
    const int bm = blockIdx.y * 128;
    const int bn = blockIdx.x * 128;
    const int z  = blockIdx.z;

    const int srow = tid >> 2;
    const int scol = (tid & 3) * 8;

    const f16* Ag = A + (size_t)z * azs + (size_t)(bm + srow) * lda + scol;
    const f16* Bg = B + (size_t)z * bzs + (size_t)(bn + srow) * ldb + scol;
    f16* AsW = As + srow * 32 + scol;
    f16* BsW = Bs + srow * 32 + scol;

    f32x4 acc[4][4];
#pragma unroll
    for (int i = 0; i < 4; ++i)
#pragma unroll
        for (int j = 0; j < 4; ++j)
            acc[i][j] = (f32x4){0.f, 0.f, 0.f, 0.f};

    const int fr = lane & 15;
    const int fk = (lane >> 4) * 8;

    for (int k0 = 0; k0 < K; k0 += 32) {
        __syncthreads();
        async_cp16(Ag + k0, AsW);
        async_cp16(Ag + k0 + (size_t)64 * lda, AsW + 64 * 32);
        async_cp16(Bg + k0, BsW);
        async_cp16(Bg + k0 + (size_t)64 * ldb, BsW + 64 * 32);
        __syncthreads();

        f16x8 af[4], bfr[4];
#pragma unroll
        for (int i = 0; i < 4; ++i)
            af[i] = *(const f16x8*)&As[(wm + i * 16 + fr) * 32 + fk];
#pragma unroll
        for (int j = 0; j < 4; ++j)
            bfr[j] = *(const f16x8*)&Bs[(wn + j * 16 + fr) * 32 + fk];
#pragma unroll
        for (int i = 0; i < 4; ++i)
#pragma unroll
            for (int j = 0; j < 4; ++j)
                acc[i][j] = __builtin_amdgcn_mfma_f32_16x16x32_f16(
                    af[i], bfr[j], acc[i][j], 0, 0, 0);
    }

    const int cn  = lane & 15;
    const int cr4 = (lane >> 4) * 4;
#pragma unroll
    for (int i = 0; i < 4; ++i) {
#pragma unroll
        for (int j = 0; j < 4; ++j) {
            const int col = bn + wn + j * 16 + cn;
            const float bv = bias ? bias[col] : 0.f;
            if constexpr (SPLITV) {
                if (col < 1024) {
#pragma unroll
                    for (int r = 0; r < 4; ++r) {
                        const int row = bm + wm + i * 16 + cr4 + r;
                        storeC(&C[(size_t)row * ldc + col], acc[i][j][r] + bv);
                    }
                } else {
                    // V column: pack 4 consecutive tokens, store to Vt
                    f16x4 pk;
#pragma unroll
                    for (int r = 0; r < 4; ++r) pk[r] = (f16)(acc[i][j][r] + bv);
                    const int vb = bm >> 10;                 // batch (tile never straddles)
                    const int s  = (bm & 1023) + wm + i * 16 + cr4;
                    *(f16x4*)&Vt[((size_t)vb * 512 + (col - 1024)) * 1024 + s] = pk;
                }
            } else {
#pragma unroll
                for (int r = 0; r < 4; ++r) {
                    const int row = bm + wm + i * 16 + cr4 + r;
                    storeC(&C[(size_t)z * czs + (size_t)row * ldc + col],
                           acc[i][j][r] + bv);
                }
            }
        }
    }
}

// ---------------------------------------------------------------------------
// Windowed causal attention via MFMA. One wave per 16-query tile; keys span
// [q0-16, q0+15].  Q/K from qkvbuf (stride 1024), V B-frags straight from
// global Vt (contiguous f16x8 along key, clamped + masked at left edge).
// out pre-offset to attn_cat slice, row stride 1536.
// ---------------------------------------------------------------------------
__global__ __launch_bounds__(256) void win_attn_mfma(
    const f16* __restrict__ qkv, const f16* __restrict__ Vt,
    f16* __restrict__ out, int w)
{
    __shared__ __align__(16) f16 Ps[4][16 * 40];   // per-wave [q16][key32]

    const int tid  = threadIdx.x;
    const int lane = tid & 63;
    const int wave = tid >> 6;
    const int b  = blockIdx.y;
    const int h  = blockIdx.z;
    const int q0 = (blockIdx.x * 4 + wave) * 16;
    const size_t bs = (size_t)b * 1024;

    const int fr  = lane & 15;
    const int grp = lane >> 4;
    const int fk8 = grp * 8;

    // Q A-frags, scaled by 1/8 * log2(e) so p = exp2(s)
    f16x8 aq[2];
    {
        const f16* qp = qkv + (bs + q0 + fr) * 1024 + h * 64 + fk8;
        aq[0] = *(const f16x8*)qp;
        aq[1] = *(const f16x8*)(qp + 32);
#pragma unroll
        for (int e = 0; e < 8; ++e) {
            aq[0][e] *= (f16)0.18033688;
            aq[1][e] *= (f16)0.18033688;
        }
    }

    // K B-frags, 2 groups of 16 keys (rows clamped; clamped keys get P=0)
    f16x8 bk[2][2];
#pragma unroll
    for (int g = 0; g < 2; ++g) {
        int krow = q0 - 16 + g * 16 + fr;
        int kcl  = krow < 0 ? 0 : krow;
        const f16* kp = qkv + (bs + kcl) * 1024 + 512 + h * 64 + fk8;
        bk[g][0] = *(const f16x8*)kp;
        bk[g][1] = *(const f16x8*)(kp + 32);
    }

    // V B-frags straight from Vt: lane reads 8 consecutive keys at fixed d
    const f16* vtb = Vt + ((size_t)b * 512 + h * 64) * 1024;
    int kbase = q0 - 16 + fk8; if (kbase < 0) kbase = 0;
    f16x8 bv[4];
#pragma unroll
    for (int j = 0; j < 4; ++j)
        bv[j] = *(const f16x8*)&vtb[(j * 16 + fr) * 1024 + kbase];

    // QK^T: 16q x 32keys, 4 MFMAs
    f32x4 s[2];
#pragma unroll
    for (int g = 0; g < 2; ++g) {
        f32x4 z = (f32x4){0.f, 0.f, 0.f, 0.f};
        z = __builtin_amdgcn_mfma_f32_16x16x32_f16(aq[0], bk[g][0], z, 0, 0, 0);
        s[g] = __builtin_amdgcn_mfma_f32_16x16x32_f16(aq[1], bk[g][1], z, 0, 0, 0);
    }

    // mask: 0 <= q-k < w AND absolute key position >= 0, then flat exp2
    float l[4] = {0.f, 0.f, 0.f, 0.f};
#pragma unroll
    for (int g = 0; g < 2; ++g) {
        const int kpos = q0 - 16 + g * 16 + fr;    // absolute key position
#pragma unroll
        for (int r = 0; r < 4; ++r) {
            const int diff = (grp * 4 + r) - (g * 16 + fr) + 16;   // q - k
            const bool ok = (diff >= 0) && (diff < w) && (kpos >= 0);
            float p = ok ? exp2f(fminf(s[g][r], 15.9f)) : 0.f;
            l[r] += p;
            Ps[wave][(grp * 4 + r) * 40 + g * 16 + fr] = (f16)p;
        }
    }

    __builtin_amdgcn_wave_barrier();   // wave-local LDS writes before reads

    // PV: O[16q][64d] = P(16x32) * V^T, 4 MFMAs
    f16x8 pa = *(const f16x8*)&Ps[wave][fr * 40 + fk8];
    f32x4 acc[4];
#pragma unroll
    for (int j = 0; j < 4; ++j) {
        f32x4 z = (f32x4){0.f, 0.f, 0.f, 0.f};
        acc[j] = __builtin_amdgcn_mfma_f32_16x16x32_f16(pa, bv[j], z, 0, 0, 0);
    }

    // reduce l across the 16-lane group, write O
#pragma unroll
    for (int r = 0; r < 4; ++r)
#pragma unroll
        for (int msk = 1; msk < 16; msk <<= 1)
            l[r] += __shfl_xor(l[r], msk, 64);

#pragma unroll
    for (int j = 0; j < 4; ++j)
#pragma unroll
        for (int r = 0; r < 4; ++r) {
            const int q = q0 + grp * 4 + r;
            out[(bs + q) * 1536 + h * 64 + j * 16 + fr] = (f16)(acc[j][r] / l[r]);
        }
}

// ---------------------------------------------------------------------------
// Full attention, MFMA flash.  K from qkvbuf (stride 1024), V from Vt
// (already [d][key] — staging is 2 vector LDS writes, no transpose).
// ---------------------------------------------------------------------------
__global__ __launch_bounds__(256) void full_attn_mfma(
    const f16* __restrict__ qkv, const f16* __restrict__ Vt,
    f16* __restrict__ out)
{
    __shared__ __align__(16) f16 Ks[64 * 72];   // [key][d]
    __shared__ __align__(16) f16 Vs[64 * 72];   // [d][key]
    __shared__ __align__(16) f16 Ps[64 * 72];   // [q][key], per-wave 16 rows

    const int tid  = threadIdx.x;
    const int lane = tid & 63;
    const int wave = tid >> 6;
    const int q0 = blockIdx.x * 128;
    const int b  = blockIdx.y;
    const int h  = blockIdx.z;
    const size_t bs = (size_t)b * 1024;

    const int fr  = lane & 15;
    const int grp = lane >> 4;
    const int fk8 = grp * 8;

    f16x8 aq[2][2];
#pragma unroll
    for (int qt = 0; qt < 2; ++qt) {
        const f16* qp = qkv + (bs + q0 + wave * 32 + qt * 16 + fr) * 1024
                        + h * 64 + fk8;
        aq[qt][0] = *(const f16x8*)qp;
        aq[qt][1] = *(const f16x8*)(qp + 32);
#pragma unroll
        for (int e = 0; e < 8; ++e) {
            aq[qt][0][e] *= (f16)0.18033688;
            aq[qt][1][e] *= (f16)0.18033688;
        }
    }

    float l[2][4];
    f32x4 acc[2][4];
#pragma unroll
    for (int qt = 0; qt < 2; ++qt)
#pragma unroll
        for (int r = 0; r < 4; ++r) {
            l[qt][r] = 0.f;
            acc[qt][r] = (f32x4){0.f, 0.f, 0.f, 0.f};
        }

    const int kr = tid >> 2, kc = (tid & 3) * 16;   // K stage: key row, d chunk
    const f16* vtrow = Vt + ((size_t)b * 512 + h * 64 + kr) * 1024;  // V stage: d row

    f16x8 ka, kb, va, vb;
    {
        const f16* kp = qkv + (bs + kr) * 1024 + 512 + h * 64 + kc;
        ka = *(const f16x8*)kp; kb = *(const f16x8*)(kp + 8);
        va = *(const f16x8*)&vtrow[kc];
        vb = *(const f16x8*)&vtrow[kc + 8];
    }

    for (int k0 = 0; k0 < 1024; k0 += 64) {
        __syncthreads();
        *(f16x8*)&Ks[kr * 72 + kc]     = ka;
        *(f16x8*)&Ks[kr * 72 + kc + 8] = kb;
        *(f16x8*)&Vs[kr * 72 + kc]     = va;
        *(f16x8*)&Vs[kr * 72 + kc + 8] = vb;
        __syncthreads();

        if (k0 + 64 < 1024) {
            const f16* kp = qkv + (bs + k0 + 64 + kr) * 1024 + 512 + h * 64 + kc;
            ka = *(const f16x8*)kp; kb = *(const f16x8*)(kp + 8);
            va = *(const f16x8*)&vtrow[k0 + 64 + kc];
            vb = *(const f16x8*)&vtrow[k0 + 64 + kc + 8];
        }

#pragma unroll
        for (int qt = 0; qt < 2; ++qt) {
            f32x4 s[4];
#pragma unroll
            for (int j = 0; j < 4; ++j) s[j] = (f32x4){0.f, 0.f, 0.f, 0.f};
#pragma unroll
            for (int j = 0; j < 4; ++j)
#pragma unroll
                for (int c = 0; c < 2; ++c) {
                    f16x8 bkf = *(const f16x8*)&Ks[(j * 16 + fr) * 72 + c * 32 + fk8];
                    s[j] = __builtin_amdgcn_mfma_f32_16x16x32_f16(
                        aq[qt][c], bkf, s[j], 0, 0, 0);
                }

#pragma unroll
            for (int j = 0; j < 4; ++j)
#pragma unroll
                for (int r = 0; r < 4; ++r) {
                    float p = exp2f(fminf(s[j][r], 15.9f));
                    l[qt][r] += p;
                    Ps[(wave * 16 + grp * 4 + r) * 72 + j * 16 + fr] = (f16)p;
                }

            __builtin_amdgcn_wave_barrier();

            f16x8 pa[2];
            pa[0] = *(const f16x8*)&Ps[(wave * 16 + fr) * 72 + fk8];
            pa[1] = *(const f16x8*)&Ps[(wave * 16 + fr) * 72 + 32 + fk8];
#pragma unroll
            for (int j = 0; j < 4; ++j)
#pragma unroll
                for (int c = 0; c < 2; ++c) {
                    f16x8 bvf = *(const f16x8*)&Vs[(j * 16 + fr) * 72 + c * 32 + fk8];
                    acc[qt][j] = __builtin_amdgcn_mfma_f32_16x16x32_f16(
                        pa[c], bvf, acc[qt][j], 0, 0, 0);
                }
            __builtin_amdgcn_wave_barrier();
        }
    }

#pragma unroll
    for (int qt = 0; qt < 2; ++qt)
#pragma unroll
        for (int r = 0; r < 4; ++r)
#pragma unroll
            for (int msk = 1; msk < 16; msk <<= 1)
                l[qt][r] += __shfl_xor(l[qt][r], msk, 64);

#pragma unroll
    for (int qt = 0; qt < 2; ++qt)
#pragma unroll
        for (int j = 0; j < 4; ++j)
#pragma unroll
            for (int r = 0; r < 4; ++r) {
                const int q = q0 + wave * 32 + qt * 16 + grp * 4 + r;
                out[(bs + q) * 1536 + h * 64 + j * 16 + fr] =
                    (f16)(acc[qt][j][r] / l[qt][r]);
            }
}

// ---------------------------------------------------------------------------
// launch
// ---------------------------------------------------------------------------
extern "C" void kernel_launch(void* const* d_in, const int* in_sizes, int n_in,
                              void* d_out, int out_size, void* d_ws, size_t ws_size,
                              hipStream_t stream)
{
    const float* x    = (const float*)d_in[0];   // [16,1024,512]
    const float* Wqkv = (const float*)d_in[1];   // [3,1536,512]
    const float* bqkv = (const float*)d_in[2];   // [3,1536]
    const float* Wo   = (const float*)d_in[3];   // [3,512,512]
    const float* bo   = (const float*)d_in[4];   // [3,512] (flat 1536)
    const float* Wf   = (const float*)d_in[5];   // [512,1536]
    const float* bfin = (const float*)d_in[6];   // [512]
    float* out = (float*)d_out;                  // [16,1024,512] fp32

    char* ws = (char*)d_ws;
    f16*   qkvbuf   = (f16*)ws;                        // 16384x1024 (33,554,432)
    f16*   Vt       = (f16*)(ws + 33554432);           // 16x512x1024 (16,777,216)
    f16*   attn_cat = (f16*)(ws + 50331648);           // 16384x1536 (50,331,648)
    f16*   wfh      = (f16*)(ws + 100663296);          // 512x1536   (1,572,864)
    f16*   WoT      = (f16*)(ws + 102236160);          // 3x512x512  (1,572,864)
    f16*   Wfo      = (f16*)(ws + 103809024);          // 512x1536   (1,572,864)
    float* bp       = (float*)(ws + 105381888);        // 512        (2,048)

    f16* xh    = (f16*)d_out;                          // 8,388,608 el (16.8 MB)
    f16* wqkvh = (f16*)((char*)d_out + 16777216);      // 2,359,296 el (4.7 MB)

    f32_to_f16<<<dim3(4096), 256, 0, stream>>>(x,    xh,    8388608);
    f32_to_f16<<<dim3(1152), 256, 0, stream>>>(Wqkv, wqkvh, 2359296);
    f32_to_f16<<<dim3(384),  256, 0, stream>>>(Wf,   wfh,   786432);
    transpose_wo<<<dim3(16, 16, 3), 256, 0, stream>>>(Wo, WoT);

    // Wfo[z] = Wf[:, 512z:512z+512] @ Wo[z]
    gemm_mfma_nt<f16, false><<<dim3(4, 4, 3), 256, 0, stream>>>(
        wfh, 1536, 512, WoT, 512, 262144, nullptr, Wfo, 1536, 512, 512, nullptr);

    // b' = bf + Wf @ bo_flat
    bias_fuse<<<dim3(128), 256, 0, stream>>>(Wf, bo, bfin, bp);

    for (int i = 0; i < 3; ++i) {
        // qkv_i = x @ Wqkv[i]^T + bqkv[i]; Q,K -> qkvbuf (ldc=1024), V -> Vt
        gemm_mfma_nt<f16, true><<<dim3(12, 128, 1), 256, 0, stream>>>(
            xh, 512, 0, wqkvh + (size_t)i * 786432, 512, 0, bqkv + i * 1536,
            qkvbuf, 1024, 0, 512, Vt);

        if (i == 0)
            win_attn_mfma<<<dim3(16, 16, 8), 256, 0, stream>>>(
                qkvbuf, Vt, attn_cat + 0 * 512, 5);
        else if (i == 1)
            win_attn_mfma<<<dim3(16, 16, 8), 256, 0, stream>>>(
                qkvbuf, Vt, attn_cat + 1 * 512, 10);
        else
            full_attn_mfma<<<dim3(8, 16, 8), 256, 0, stream>>>(
                qkvbuf, Vt, attn_cat + 2 * 512);
    }

    // out = attn_cat @ Wfo^T + b'  (fp32 out), M=16384 N=512 K=1536
    gemm_mfma_nt<float, false><<<dim3(4, 128, 1), 256, 0, stream>>>(
        attn_cat, 1536, 0, Wfo, 1536, 0, bp, out, 512, 0, 1536, nullptr);
}